// Round 7
// baseline (139.968 us; speedup 1.0000x reference)
//
#include <hip/hip_runtime.h>
#include <math.h>

// Problem constants (SelectiveSSM)
#define BATCH   2
#define SEQLEN  512
#define DI      4096      // d_inner
#define DS      16        // d_state
#define RDT     128       // dt_rank
#define RTOT    160       // dt_rank + 2*d_state
#define BL      1024      // BATCH*SEQLEN rows

#define KSP     8         // k-split slabs (512-wide each)

#define LOG2E 1.44269504088896340736f
#define LN2   0.69314718055994530942f

typedef __bf16 bf16;
typedef bf16  bf16x8 __attribute__((ext_vector_type(8)));
typedef bf16  bf16x4 __attribute__((ext_vector_type(4)));
typedef float f32x4  __attribute__((ext_vector_type(4)));

__device__ __forceinline__ bf16x8 cvt8(const float4 a, const float4 b) {
  bf16x8 r;
  r[0] = (bf16)a.x; r[1] = (bf16)a.y; r[2] = (bf16)a.z; r[3] = (bf16)a.w;
  r[4] = (bf16)b.x; r[5] = (bf16)b.y; r[6] = (bf16)b.z; r[7] = (bf16)b.w;
  return r;
}

__device__ __forceinline__ bf16x8 cvt8s(const float4 a, const float4 b, const float s) {
  bf16x8 r;
  r[0] = (bf16)(s * a.x); r[1] = (bf16)(s * a.y); r[2] = (bf16)(s * a.z); r[3] = (bf16)(s * a.w);
  r[4] = (bf16)(s * b.x); r[5] = (bf16)(s * b.y); r[6] = (bf16)(s * b.z); r[7] = (bf16)(s * b.w);
  return r;
}

// ---------------------------------------------------------------------------
// GEMM1 k-split partials — N-partitioned waves, NO LDS, NO barriers.
// Grid (64 M-tiles x 8 k-splits) = 512 blocks x 320 threads (5 waves).
// Wave w owns output n-tiles {2w, 2w+1} (10 tiles = 160 cols) over the full
// 512-wide K slice of this ks: a pure load->cvt->MFMA stream, 32 MFMA/wave,
// accumulator stored straight to the slab (16-lane contiguous segments).
// Replaces the K-across-waves version whose 42 KB LDS + 2 barriers + two-
// stage cross-wave add made it sync/latency-bound (~25-30 us).
// LDS=0 -> 10 waves/CU.
// ---------------------------------------------------------------------------
__global__ __launch_bounds__(320) void gemm_part(const float* __restrict__ x,
                                                 const float* __restrict__ W,
                                                 bf16* __restrict__ dtp,
                                                 float* __restrict__ bcp) {
  const int tid = threadIdx.x;
  const int w = tid >> 6;                // 0..4
  const int lane = tid & 63;
  const int m = lane & 15;
  const int q = lane >> 4;
  const int row0 = blockIdx.x * 16;
  const int ks = blockIdx.y;
  const int k0 = ks * (DI / KSP);        // 512-wide K slice
  const int ntA = 2 * w;
  const int ntB = 2 * w + 1;

  f32x4 accA = {}, accB = {};
  const float* ap  = x + (size_t)(row0 + m) * DI + k0 + 8 * q;
  const float* wpA = W + (size_t)(ntA * 16 + m) * DI + k0 + 8 * q;
  const float* wpB = W + (size_t)(ntB * 16 + m) * DI + k0 + 8 * q;

#pragma unroll 4
  for (int kk = 0; kk < 512; kk += 32) {
    bf16x8 af = cvt8(*(const float4*)(ap + kk),  *(const float4*)(ap + kk + 4));
    bf16x8 bA = cvt8(*(const float4*)(wpA + kk), *(const float4*)(wpA + kk + 4));
    bf16x8 bB = cvt8(*(const float4*)(wpB + kk), *(const float4*)(wpB + kk + 4));
    accA = __builtin_amdgcn_mfma_f32_16x16x32_bf16(af, bA, accA, 0, 0, 0);
    accB = __builtin_amdgcn_mfma_f32_16x16x32_bf16(af, bB, accB, 0, 0, 0);
  }

  // C/D layout: col = m (N dim), row = 4q + r (M dim). Direct slab stores.
  // Waves 0-3 (nt 0-7) -> dtp bf16; wave 4 (nt 8,9) -> bcp fp32 (B then C).
  if (ntA < 8) {
    bf16* dA = dtp + (size_t)ks * (BL * RDT) + ntA * 16 + m;
    bf16* dB = dtp + (size_t)ks * (BL * RDT) + ntB * 16 + m;
#pragma unroll
    for (int r = 0; r < 4; ++r) {
      const size_t row = row0 + 4 * q + r;
      dA[row * RDT] = (bf16)accA[r];
      dB[row * RDT] = (bf16)accB[r];
    }
  } else {
    float* bA = bcp + (size_t)ks * (BL * 32) + m;        // B cols 0..15
    float* bB = bcp + (size_t)ks * (BL * 32) + 16 + m;   // C cols 0..15
#pragma unroll
    for (int r = 0; r < 4; ++r) {
      const size_t row = row0 + 4 * q + r;
      bA[row * 32] = accA[r];
      bB[row * 32] = accB[r];
    }
  }
}

// ---------------------------------------------------------------------------
// Fold the 8 k-split slabs into the scan's compact inputs:
//   dtin bf16 [1024][128], BCf fp32 [1024][32].
// 160 blocks x 256 threads, 4 outputs/thread; ~12 MB L2-resident reads.
// ---------------------------------------------------------------------------
__global__ __launch_bounds__(256) void reduce_slabs(const bf16* __restrict__ dtp,
                                                    const float* __restrict__ bcp,
                                                    bf16* __restrict__ dtin,
                                                    float* __restrict__ BCf) {
  const int o = (blockIdx.x * 256 + threadIdx.x) * 4;
  const int row = o / RTOT;
  const int col = o - row * RTOT;   // multiple of 4; never straddles rows
  if (col < RDT) {
    float s0 = 0.f, s1 = 0.f, s2 = 0.f, s3 = 0.f;
#pragma unroll
    for (int ks = 0; ks < KSP; ++ks) {
      bf16x4 v = *(const bf16x4*)(dtp + (size_t)ks * (BL * RDT) + (size_t)row * RDT + col);
      s0 += (float)v[0]; s1 += (float)v[1]; s2 += (float)v[2]; s3 += (float)v[3];
    }
    bf16x4 ob;
    ob[0] = (bf16)s0; ob[1] = (bf16)s1; ob[2] = (bf16)s2; ob[3] = (bf16)s3;
    *(bf16x4*)(dtin + (size_t)row * RDT + col) = ob;
  } else {
    float4 s = make_float4(0.f, 0.f, 0.f, 0.f);
#pragma unroll
    for (int ks = 0; ks < KSP; ++ks) {
      float4 v = *(const float4*)&bcp[(size_t)ks * (BL * 32) + (size_t)row * 32 + (col - RDT)];
      s.x += v.x; s.y += v.y; s.z += v.z; s.w += v.w;
    }
    *(float4*)&BCf[(size_t)row * 32 + (col - RDT)] = s;
  }
}

// ---------------------------------------------------------------------------
// 16-lane (DPP row) sum reduction on the VALU pipe. Result valid in lane 15
// of each 16-lane row.
// ---------------------------------------------------------------------------
__device__ __forceinline__ float row16_reduce_add(float p) {
  p += __int_as_float(__builtin_amdgcn_update_dpp(
      0, __float_as_int(p), 0x111, 0xf, 0xf, true));  // row_shr:1
  p += __int_as_float(__builtin_amdgcn_update_dpp(
      0, __float_as_int(p), 0x112, 0xf, 0xf, true));  // row_shr:2
  p += __int_as_float(__builtin_amdgcn_update_dpp(
      0, __float_as_int(p), 0x114, 0xf, 0xf, true));  // row_shr:4
  p += __int_as_float(__builtin_amdgcn_update_dpp(
      0, __float_as_int(p), 0x118, 0xf, 0xf, true));  // row_shr:8
  return p;
}

// ---------------------------------------------------------------------------
// Fused GEMM2 + selective scan — byte-identical to round 6 (135.45 us best):
//  - uS = softplus(dt)*x staged once per (d,t).
//  - g-loop unrolled; s_setprio(1) around the serial core.
//  - exp2/log2-domain softplus + per-step exponential (fast intrinsics).
//  - D*x deferred to the y-store phase.
// ---------------------------------------------------------------------------
#define TC  64
#define TCP 68
#define NCH (SEQLEN / TC)

__global__ __launch_bounds__(256) void scan_fused(const float* __restrict__ x,
                                                  const float* __restrict__ A_log,
                                                  const float* __restrict__ Dvec,
                                                  const float* __restrict__ BCf,
                                                  const bf16* __restrict__ dtin,
                                                  const float* __restrict__ dtw,
                                                  const float* __restrict__ dtb,
                                                  float* __restrict__ out) {
  __shared__ __align__(16) float dtS[16][TCP];  // [dc][t]  softplus(dt)
  __shared__ __align__(16) float uS[16][TCP];   // [dc][t]  softplus(dt)*x
  __shared__ __align__(16) float BS[16][TCP];   // [n][t]
  __shared__ __align__(16) float CS[16][TCP];   // [n][t]
  __shared__ __align__(16) float yS[TC][16];    // [t][dc]

  const int bid = blockIdx.x;         // 0..511
  const int b = bid >> 8;
  const int d0 = (bid & 255) * 16;
  const int tid = threadIdx.x;
  const int n = tid & 15;             // state (scan) / MFMA m
  const int dc = tid >> 4;            // channel (scan)
  const int d = d0 + dc;
  const int w = tid >> 6;             // wave id (MFMA staging)
  const int m = tid & 15;
  const int q = (tid >> 4) & 3;

  const float A2 = -LOG2E * __expf(A_log[d * DS + n]);   // exp2-folded A
  const float bias2 = dtb[d0 + m] * LOG2E;

  // dtw B-fragments: chunk-invariant, scaled by log2e, cast inline (once)
  bf16x8 bfragW[4];
#pragma unroll
  for (int k = 0; k < 4; ++k) {
    const float* p = dtw + (size_t)(d0 + m) * RDT + 32 * k + 8 * q;
    float4 w0 = *(const float4*)p;
    float4 w1 = *(const float4*)(p + 4);
    bfragW[k] = cvt8s(w0, w1, LOG2E);
  }

  // loader mapping for B/C/y: thread -> row lt (0..63), 4-elem slice lf
  const int lt = tid >> 2;
  const int lf = (tid & 3) * 4;
  const int rowbase = b * SEQLEN;
  const float4 Dv4 = *(const float4*)&Dvec[d0 + lf];  // for deferred D*x

  // MFMA-thread x rows: t = 16w + 4q + r within chunk (matches D layout)
  const int xtrow = rowbase + 16 * w + 4 * q;

  // prefetch chunk 0
  bf16x8 afrag[4];
  float xm[4];
  float4 rx, rB, rC, rx_prev;
  {
    const int arow = rowbase + 16 * w + m;
#pragma unroll
    for (int k = 0; k < 4; ++k)
      afrag[k] = *(const bf16x8*)(dtin + (size_t)arow * RDT + 32 * k + 8 * q);
#pragma unroll
    for (int r = 0; r < 4; ++r)
      xm[r] = x[(size_t)(xtrow + r) * DI + d0 + m];
    const int row = rowbase + lt;
    rx = *(const float4*)&x[(size_t)row * DI + d0 + lf];
    rB = *(const float4*)&BCf[row * 32 + lf];
    rC = *(const float4*)&BCf[row * 32 + 16 + lf];
  }

  float h = 0.f;

  for (int c = 0; c < NCH; ++c) {
    if (c > 0) __syncthreads();   // prev compute (LDS reads + yS writes) done

    // ---- stage dt & u via MFMA + softplus (log2 domain) ----
    {
      f32x4 acc = {};
#pragma unroll
      for (int k = 0; k < 4; ++k)
        acc = __builtin_amdgcn_mfma_f32_16x16x32_bf16(afrag[k], bfragW[k], acc, 0, 0, 0);
      // D layout: col m = channel, row 4q+r = timestep within 16-row tile
#pragma unroll
      for (int r = 0; r < 4; ++r) {
        const float z2 = acc[r] + bias2;             // = z * log2(e)
        const float dts =
            (z2 > 28.854f) ? z2 * LN2
                           : LN2 * __builtin_amdgcn_logf(1.f + __builtin_amdgcn_exp2f(z2));
        dtS[m][16 * w + 4 * q + r] = dts;
        uS[m][16 * w + 4 * q + r] = dts * xm[r];
      }
    }
    // ---- stage B, C (transposed) ----
    {
      const float rBa[4] = {rB.x, rB.y, rB.z, rB.w};
      const float rCa[4] = {rC.x, rC.y, rC.z, rC.w};
#pragma unroll
      for (int j = 0; j < 4; ++j) {
        BS[lf + j][lt] = rBa[j];
        CS[lf + j][lt] = rCa[j];
      }
    }
    // ---- store previous chunk's y (+ deferred D*x via rx_prev) ----
    if (c > 0) {
      const int prow = rowbase + (c - 1) * TC + lt;
      float4 yv = *(const float4*)&yS[lt][lf];
      float4 o4;
      o4.x = fmaf(Dv4.x, rx_prev.x, yv.x);
      o4.y = fmaf(Dv4.y, rx_prev.y, yv.y);
      o4.z = fmaf(Dv4.z, rx_prev.z, yv.z);
      o4.w = fmaf(Dv4.w, rx_prev.w, yv.w);
      *(float4*)&out[(size_t)prow * DI + d0 + lf] = o4;
    }
    rx_prev = rx;                 // keep chunk c's x for its y-store

    __syncthreads();              // tiles ready; yS reads done

    // ---- prefetch next chunk ----
    if (c < NCH - 1) {
      const int arow = rowbase + (c + 1) * TC + 16 * w + m;
#pragma unroll
      for (int k = 0; k < 4; ++k)
        afrag[k] = *(const bf16x8*)(dtin + (size_t)arow * RDT + 32 * k + 8 * q);
#pragma unroll
      for (int r = 0; r < 4; ++r)
        xm[r] = x[(size_t)(xtrow + (c + 1) * TC + r) * DI + d0 + m];
      const int row = rowbase + (c + 1) * TC + lt;
      rx = *(const float4*)&x[(size_t)row * DI + d0 + lf];
      rB = *(const float4*)&BCf[row * 32 + lf];
      rC = *(const float4*)&BCf[row * 32 + 16 + lf];
    }

    // ---- 64 steps: 8 groups of 8, fully unrolled register batches ----
    __builtin_amdgcn_s_setprio(1);
#pragma unroll
    for (int g = 0; g < 8; ++g) {
      const int t0 = 8 * g;
      const float4 dv0 = *(const float4*)&dtS[dc][t0];
      const float4 dv1 = *(const float4*)&dtS[dc][t0 + 4];
      const float4 uv0 = *(const float4*)&uS[dc][t0];
      const float4 uv1 = *(const float4*)&uS[dc][t0 + 4];
      const float4 Bv0 = *(const float4*)&BS[n][t0];
      const float4 Bv1 = *(const float4*)&BS[n][t0 + 4];
      const float4 Cv0 = *(const float4*)&CS[n][t0];
      const float4 Cv1 = *(const float4*)&CS[n][t0 + 4];
      const float dt[8] = {dv0.x, dv0.y, dv0.z, dv0.w, dv1.x, dv1.y, dv1.z, dv1.w};
      const float uv[8] = {uv0.x, uv0.y, uv0.z, uv0.w, uv1.x, uv1.y, uv1.z, uv1.w};
      const float Bv[8] = {Bv0.x, Bv0.y, Bv0.z, Bv0.w, Bv1.x, Bv1.y, Bv1.z, Bv1.w};
      const float Cv[8] = {Cv0.x, Cv0.y, Cv0.z, Cv0.w, Cv1.x, Cv1.y, Cv1.z, Cv1.w};

      float e[8], u[8], p[8];
#pragma unroll
      for (int j = 0; j < 8; ++j) {       // independent: pipelines freely
        e[j] = __builtin_amdgcn_exp2f(dt[j] * A2);   // 1 mul + v_exp_f32
        u[j] = uv[j] * Bv[j];             // dt*x pre-staged: 1 mul
      }
#pragma unroll
      for (int j = 0; j < 8; ++j) {       // the only true serial chain
        h = fmaf(e[j], h, u[j]);
        p[j] = h * Cv[j];
      }
#pragma unroll
      for (int j = 0; j < 8; ++j)         // 8 independent DPP chains
        p[j] = row16_reduce_add(p[j]);
      if (n == 15) {
#pragma unroll
        for (int j = 0; j < 8; ++j)
          yS[t0 + j][dc] = p[j];          // D*x applied at store time
      }
    }
    __builtin_amdgcn_s_setprio(0);
  }

  __syncthreads();
  {
    const int prow = rowbase + (NCH - 1) * TC + lt;
    float4 yv = *(const float4*)&yS[lt][lf];
    float4 o4;
    o4.x = fmaf(Dv4.x, rx_prev.x, yv.x);
    o4.y = fmaf(Dv4.y, rx_prev.y, yv.y);
    o4.z = fmaf(Dv4.z, rx_prev.z, yv.z);
    o4.w = fmaf(Dv4.w, rx_prev.w, yv.w);
    *(float4*)&out[(size_t)prow * DI + d0 + lf] = o4;
  }
}

// ---------------------------------------------------------------------------
extern "C" void kernel_launch(void* const* d_in, const int* in_sizes, int n_in,
                              void* d_out, int out_size, void* d_ws, size_t ws_size,
                              hipStream_t stream) {
  const float* x     = (const float*)d_in[0];  // (2,512,4096)
  const float* A_log = (const float*)d_in[1];  // (4096,16)
  const float* Dv    = (const float*)d_in[2];  // (4096,)
  const float* W     = (const float*)d_in[3];  // (160,4096)
  const float* dtw   = (const float*)d_in[4];  // (4096,128)
  const float* dtb   = (const float*)d_in[5];  // (4096,)
  float* out = (float*)d_out;

  // Workspace: dtp [8][1024][128] bf16 (2 MB) + bcp [8][1024][32] f32 (1 MB)
  //          + dtin [1024][128] bf16 (256 KB) + BCf [1024][32] f32 (128 KB)
  char* ws = (char*)d_ws;
  bf16*  dtp  = (bf16*)ws;
  float* bcp  = (float*)(ws + (size_t)KSP * BL * RDT * sizeof(bf16));
  bf16*  dtin = (bf16*)(ws + (size_t)KSP * BL * RDT * sizeof(bf16)
                           + (size_t)KSP * BL * 32 * sizeof(float));
  float* BCf  = (float*)(ws + (size_t)KSP * BL * RDT * sizeof(bf16)
                            + (size_t)KSP * BL * 32 * sizeof(float)
                            + (size_t)BL * RDT * sizeof(bf16));

  gemm_part<<<dim3(64, KSP), 320, 0, stream>>>(x, W, dtp, bcp);
  reduce_slabs<<<dim3(160), 256, 0, stream>>>(dtp, bcp, dtin, BCf);
  scan_fused<<<dim3(512), 256, 0, stream>>>(x, A_log, Dv, BCf, dtin, dtw, dtb, out);
}

// Round 8
// 135.420 us; speedup vs baseline: 1.0336x; 1.0336x over previous
//
#include <hip/hip_runtime.h>
#include <math.h>

// Problem constants (SelectiveSSM)
#define BATCH   2
#define SEQLEN  512
#define DI      4096      // d_inner
#define DS      16        // d_state
#define RDT     128       // dt_rank
#define RTOT    160       // dt_rank + 2*d_state
#define BL      1024      // BATCH*SEQLEN rows

#define KSP     8         // k-split slabs (512-wide each)

#define LOG2E 1.44269504088896340736f
#define LN2   0.69314718055994530942f

typedef __bf16 bf16;
typedef bf16  bf16x8 __attribute__((ext_vector_type(8)));
typedef bf16  bf16x4 __attribute__((ext_vector_type(4)));
typedef float f32x4  __attribute__((ext_vector_type(4)));

__device__ __forceinline__ bf16x8 cvt8(const float4 a, const float4 b) {
  bf16x8 r;
  r[0] = (bf16)a.x; r[1] = (bf16)a.y; r[2] = (bf16)a.z; r[3] = (bf16)a.w;
  r[4] = (bf16)b.x; r[5] = (bf16)b.y; r[6] = (bf16)b.z; r[7] = (bf16)b.w;
  return r;
}

__device__ __forceinline__ bf16x8 cvt8s(const float4 a, const float4 b, const float s) {
  bf16x8 r;
  r[0] = (bf16)(s * a.x); r[1] = (bf16)(s * a.y); r[2] = (bf16)(s * a.z); r[3] = (bf16)(s * a.w);
  r[4] = (bf16)(s * b.x); r[5] = (bf16)(s * b.y); r[6] = (bf16)(s * b.z); r[7] = (bf16)(s * b.w);
  return r;
}

// ---------------------------------------------------------------------------
// GEMM1 k-split partials — round-6 K-split version (part of the 135.45 best;
// round-7's N-partitioned no-LDS variant regressed: scalar 2B slab stores at
// 256B stride + 5x redundant x reads). Grid (64 M-tiles x 8 k-splits) = 512
// blocks x 512 threads. Wave w covers K slice [ks*512 + w*64, +64); two-
// stage LDS reduce; packed stores: cols 0..127 -> dtp bf16, 128..159 -> bcp.
// ---------------------------------------------------------------------------
#define LPAD 164   // 164 mod 32 = 4: q-groups land on distinct banks

__global__ __launch_bounds__(512) void gemm_part(const float* __restrict__ x,
                                                 const float* __restrict__ W,
                                                 bf16* __restrict__ dtp,
                                                 float* __restrict__ bcp) {
  __shared__ float Lred[4][16 * LPAD];   // 41,984 B
  const int tid = threadIdx.x;
  const int w = tid >> 6;                // 0..7
  const int lane = tid & 63;
  const int m = lane & 15;
  const int q = lane >> 4;
  const int row0 = blockIdx.x * 16;
  const int ks = blockIdx.y;
  const int k0 = ks * (DI / KSP) + w * 64;

  f32x4 acc[10] = {};
  const float* ap = x + (size_t)(row0 + m) * DI + k0 + 8 * q;
  const float* wp = W + (size_t)m * DI + k0 + 8 * q;

#pragma unroll
  for (int kk = 0; kk < 64; kk += 32) {
    float4 a0 = *(const float4*)(ap + kk);
    float4 a1 = *(const float4*)(ap + kk + 4);
    bf16x8 af = cvt8(a0, a1);
#pragma unroll
    for (int nt = 0; nt < 10; ++nt) {
      const float* wq = wp + (size_t)nt * 16 * DI + kk;
      float4 b0 = *(const float4*)(wq);
      float4 b1 = *(const float4*)(wq + 4);
      acc[nt] = __builtin_amdgcn_mfma_f32_16x16x32_bf16(af, cvt8(b0, b1), acc[nt], 0, 0, 0);
    }
  }

  // C/D layout: col = m (N dim), row = 4q + r (M dim). Two-stage reduce.
  if (w < 4) {
#pragma unroll
    for (int nt = 0; nt < 10; ++nt)
#pragma unroll
      for (int r = 0; r < 4; ++r)
        Lred[w][(4 * q + r) * LPAD + nt * 16 + m] = acc[nt][r];
  }
  __syncthreads();
  if (w >= 4) {
#pragma unroll
    for (int nt = 0; nt < 10; ++nt)
#pragma unroll
      for (int r = 0; r < 4; ++r)
        Lred[w - 4][(4 * q + r) * LPAD + nt * 16 + m] += acc[nt][r];
  }
  __syncthreads();

#pragma unroll
  for (int i = 0; i < 5; ++i) {
    const int o = i * 512 + tid;           // 0..2559 over 16x160 outputs
    const int row = o / 160;
    const int col = o - row * 160;
    const int a = row * LPAD + col;
    const float s = Lred[0][a] + Lred[1][a] + Lred[2][a] + Lred[3][a];
    if (col < RDT) dtp[(size_t)ks * (BL * RDT) + (size_t)(row0 + row) * RDT + col] = (bf16)s;
    else           bcp[(size_t)ks * (BL * 32) + (size_t)(row0 + row) * 32 + (col - RDT)] = s;
  }
}

// ---------------------------------------------------------------------------
// Fold the 8 k-split slabs into the scan's compact inputs:
//   dtin bf16 [1024][128], BCf fp32 [1024][32].
// ---------------------------------------------------------------------------
__global__ __launch_bounds__(256) void reduce_slabs(const bf16* __restrict__ dtp,
                                                    const float* __restrict__ bcp,
                                                    bf16* __restrict__ dtin,
                                                    float* __restrict__ BCf) {
  const int o = (blockIdx.x * 256 + threadIdx.x) * 4;
  const int row = o / RTOT;
  const int col = o - row * RTOT;   // multiple of 4; never straddles rows
  if (col < RDT) {
    float s0 = 0.f, s1 = 0.f, s2 = 0.f, s3 = 0.f;
#pragma unroll
    for (int ks = 0; ks < KSP; ++ks) {
      bf16x4 v = *(const bf16x4*)(dtp + (size_t)ks * (BL * RDT) + (size_t)row * RDT + col);
      s0 += (float)v[0]; s1 += (float)v[1]; s2 += (float)v[2]; s3 += (float)v[3];
    }
    bf16x4 ob;
    ob[0] = (bf16)s0; ob[1] = (bf16)s1; ob[2] = (bf16)s2; ob[3] = (bf16)s3;
    *(bf16x4*)(dtin + (size_t)row * RDT + col) = ob;
  } else {
    float4 s = make_float4(0.f, 0.f, 0.f, 0.f);
#pragma unroll
    for (int ks = 0; ks < KSP; ++ks) {
      float4 v = *(const float4*)&bcp[(size_t)ks * (BL * 32) + (size_t)row * 32 + (col - RDT)];
      s.x += v.x; s.y += v.y; s.z += v.z; s.w += v.w;
    }
    *(float4*)&BCf[(size_t)row * 32 + (col - RDT)] = s;
  }
}

// ---------------------------------------------------------------------------
// 16-lane (DPP row) sum reduction on the VALU pipe. Result valid in lane 15
// of each 16-lane row.
// ---------------------------------------------------------------------------
__device__ __forceinline__ float row16_reduce_add(float p) {
  p += __int_as_float(__builtin_amdgcn_update_dpp(
      0, __float_as_int(p), 0x111, 0xf, 0xf, true));  // row_shr:1
  p += __int_as_float(__builtin_amdgcn_update_dpp(
      0, __float_as_int(p), 0x112, 0xf, 0xf, true));  // row_shr:2
  p += __int_as_float(__builtin_amdgcn_update_dpp(
      0, __float_as_int(p), 0x114, 0xf, 0xf, true));  // row_shr:4
  p += __int_as_float(__builtin_amdgcn_update_dpp(
      0, __float_as_int(p), 0x118, 0xf, 0xf, true));  // row_shr:8
  return p;
}

// ---------------------------------------------------------------------------
// Fused GEMM2 + selective scan — round-6 core with DOUBLE-BUFFERED LDS:
// one __syncthreads per chunk (was 2). Per-iteration order:
//   stage(c) [buf c&1] -> BARRIER -> y-store(c-1) [yS[(c-1)&1]] ->
//   rx_prev=rx -> prefetch(c+1) -> core(c) [reads buf c&1, writes yS[c&1]]
// Hazards: stage(c) vs core(c-1) on opposite buffers (race dbuf removes);
// yS write(core c)->read(y-store c+1) and read->rewrite(core c+1) each
// separated by exactly one barrier. LDS 43 KB, still 2 blocks/CU.
// ---------------------------------------------------------------------------
#define TC  64
#define TCP 68
#define NCH (SEQLEN / TC)

__global__ __launch_bounds__(256) void scan_fused(const float* __restrict__ x,
                                                  const float* __restrict__ A_log,
                                                  const float* __restrict__ Dvec,
                                                  const float* __restrict__ BCf,
                                                  const bf16* __restrict__ dtin,
                                                  const float* __restrict__ dtw,
                                                  const float* __restrict__ dtb,
                                                  float* __restrict__ out) {
  __shared__ __align__(16) float dtS[2][16][TCP];  // [buf][dc][t] softplus(dt)
  __shared__ __align__(16) float uS[2][16][TCP];   // [buf][dc][t] softplus*x
  __shared__ __align__(16) float BS[2][16][TCP];   // [buf][n][t]
  __shared__ __align__(16) float CS[2][16][TCP];   // [buf][n][t]
  __shared__ __align__(16) float yS[2][TC][16];    // [buf][t][dc]

  const int bid = blockIdx.x;         // 0..511
  const int b = bid >> 8;
  const int d0 = (bid & 255) * 16;
  const int tid = threadIdx.x;
  const int n = tid & 15;             // state (scan) / MFMA m
  const int dc = tid >> 4;            // channel (scan)
  const int d = d0 + dc;
  const int w = tid >> 6;             // wave id (MFMA staging)
  const int m = tid & 15;
  const int q = (tid >> 4) & 3;

  const float A2 = -LOG2E * __expf(A_log[d * DS + n]);   // exp2-folded A
  const float bias2 = dtb[d0 + m] * LOG2E;

  // dtw B-fragments: chunk-invariant, scaled by log2e, cast inline (once)
  bf16x8 bfragW[4];
#pragma unroll
  for (int k = 0; k < 4; ++k) {
    const float* p = dtw + (size_t)(d0 + m) * RDT + 32 * k + 8 * q;
    float4 w0 = *(const float4*)p;
    float4 w1 = *(const float4*)(p + 4);
    bfragW[k] = cvt8s(w0, w1, LOG2E);
  }

  // loader mapping for B/C/y: thread -> row lt (0..63), 4-elem slice lf
  const int lt = tid >> 2;
  const int lf = (tid & 3) * 4;
  const int rowbase = b * SEQLEN;
  const float4 Dv4 = *(const float4*)&Dvec[d0 + lf];  // for deferred D*x

  // MFMA-thread x rows: t = 16w + 4q + r within chunk (matches D layout)
  const int xtrow = rowbase + 16 * w + 4 * q;

  // prefetch chunk 0
  bf16x8 afrag[4];
  float xm[4];
  float4 rx, rB, rC, rx_prev;
  {
    const int arow = rowbase + 16 * w + m;
#pragma unroll
    for (int k = 0; k < 4; ++k)
      afrag[k] = *(const bf16x8*)(dtin + (size_t)arow * RDT + 32 * k + 8 * q);
#pragma unroll
    for (int r = 0; r < 4; ++r)
      xm[r] = x[(size_t)(xtrow + r) * DI + d0 + m];
    const int row = rowbase + lt;
    rx = *(const float4*)&x[(size_t)row * DI + d0 + lf];
    rB = *(const float4*)&BCf[row * 32 + lf];
    rC = *(const float4*)&BCf[row * 32 + 16 + lf];
  }

  float h = 0.f;

  for (int c = 0; c < NCH; ++c) {
    const int pb = c & 1;
    float (*dtC)[TCP] = dtS[pb];
    float (*uC)[TCP]  = uS[pb];
    float (*BC_)[TCP] = BS[pb];
    float (*CC_)[TCP] = CS[pb];
    float (*yC)[16]   = yS[pb];
    float (*yP)[16]   = yS[pb ^ 1];

    // ---- stage dt & u via MFMA + softplus (log2 domain) into buf pb ----
    {
      f32x4 acc = {};
#pragma unroll
      for (int k = 0; k < 4; ++k)
        acc = __builtin_amdgcn_mfma_f32_16x16x32_bf16(afrag[k], bfragW[k], acc, 0, 0, 0);
      // D layout: col m = channel, row 4q+r = timestep within 16-row tile
#pragma unroll
      for (int r = 0; r < 4; ++r) {
        const float z2 = acc[r] + bias2;             // = z * log2(e)
        const float dts =
            (z2 > 28.854f) ? z2 * LN2
                           : LN2 * __builtin_amdgcn_logf(1.f + __builtin_amdgcn_exp2f(z2));
        dtC[m][16 * w + 4 * q + r] = dts;
        uC[m][16 * w + 4 * q + r] = dts * xm[r];
      }
    }
    // ---- stage B, C (transposed) into buf pb ----
    {
      const float rBa[4] = {rB.x, rB.y, rB.z, rB.w};
      const float rCa[4] = {rC.x, rC.y, rC.z, rC.w};
#pragma unroll
      for (int j = 0; j < 4; ++j) {
        BC_[lf + j][lt] = rBa[j];
        CC_[lf + j][lt] = rCa[j];
      }
    }

    __syncthreads();   // the ONE barrier: stage(c) visible; core(c-1) done

    // ---- store chunk c-1's y (reads yS[pb^1], written by core(c-1)) ----
    if (c > 0) {
      const int prow = rowbase + (c - 1) * TC + lt;
      float4 yv = *(const float4*)&yP[lt][lf];
      float4 o4;
      o4.x = fmaf(Dv4.x, rx_prev.x, yv.x);
      o4.y = fmaf(Dv4.y, rx_prev.y, yv.y);
      o4.z = fmaf(Dv4.z, rx_prev.z, yv.z);
      o4.w = fmaf(Dv4.w, rx_prev.w, yv.w);
      *(float4*)&out[(size_t)prow * DI + d0 + lf] = o4;
    }
    rx_prev = rx;                 // keep chunk c's x for its y-store

    // ---- prefetch chunk c+1 (registers only) ----
    if (c < NCH - 1) {
      const int arow = rowbase + (c + 1) * TC + 16 * w + m;
#pragma unroll
      for (int k = 0; k < 4; ++k)
        afrag[k] = *(const bf16x8*)(dtin + (size_t)arow * RDT + 32 * k + 8 * q);
#pragma unroll
      for (int r = 0; r < 4; ++r)
        xm[r] = x[(size_t)(xtrow + (c + 1) * TC + r) * DI + d0 + m];
      const int row = rowbase + (c + 1) * TC + lt;
      rx = *(const float4*)&x[(size_t)row * DI + d0 + lf];
      rB = *(const float4*)&BCf[row * 32 + lf];
      rC = *(const float4*)&BCf[row * 32 + 16 + lf];
    }

    // ---- 64 steps: 8 groups of 8, fully unrolled register batches ----
    __builtin_amdgcn_s_setprio(1);
#pragma unroll
    for (int g = 0; g < 8; ++g) {
      const int t0 = 8 * g;
      const float4 dv0 = *(const float4*)&dtC[dc][t0];
      const float4 dv1 = *(const float4*)&dtC[dc][t0 + 4];
      const float4 uv0 = *(const float4*)&uC[dc][t0];
      const float4 uv1 = *(const float4*)&uC[dc][t0 + 4];
      const float4 Bv0 = *(const float4*)&BC_[n][t0];
      const float4 Bv1 = *(const float4*)&BC_[n][t0 + 4];
      const float4 Cv0 = *(const float4*)&CC_[n][t0];
      const float4 Cv1 = *(const float4*)&CC_[n][t0 + 4];
      const float dt[8] = {dv0.x, dv0.y, dv0.z, dv0.w, dv1.x, dv1.y, dv1.z, dv1.w};
      const float uv[8] = {uv0.x, uv0.y, uv0.z, uv0.w, uv1.x, uv1.y, uv1.z, uv1.w};
      const float Bv[8] = {Bv0.x, Bv0.y, Bv0.z, Bv0.w, Bv1.x, Bv1.y, Bv1.z, Bv1.w};
      const float Cv[8] = {Cv0.x, Cv0.y, Cv0.z, Cv0.w, Cv1.x, Cv1.y, Cv1.z, Cv1.w};

      float e[8], u[8], p[8];
#pragma unroll
      for (int j = 0; j < 8; ++j) {       // independent: pipelines freely
        e[j] = __builtin_amdgcn_exp2f(dt[j] * A2);   // 1 mul + v_exp_f32
        u[j] = uv[j] * Bv[j];             // dt*x pre-staged: 1 mul
      }
#pragma unroll
      for (int j = 0; j < 8; ++j) {       // the only true serial chain
        h = fmaf(e[j], h, u[j]);
        p[j] = h * Cv[j];
      }
#pragma unroll
      for (int j = 0; j < 8; ++j)         // 8 independent DPP chains
        p[j] = row16_reduce_add(p[j]);
      if (n == 15) {
#pragma unroll
        for (int j = 0; j < 8; ++j)
          yC[t0 + j][dc] = p[j];          // D*x applied at store time
      }
    }
    __builtin_amdgcn_s_setprio(0);
  }

  __syncthreads();
  {
    const int prow = rowbase + (NCH - 1) * TC + lt;
    float4 yv = *(const float4*)&yS[(NCH - 1) & 1][lt][lf];
    float4 o4;
    o4.x = fmaf(Dv4.x, rx_prev.x, yv.x);
    o4.y = fmaf(Dv4.y, rx_prev.y, yv.y);
    o4.z = fmaf(Dv4.z, rx_prev.z, yv.z);
    o4.w = fmaf(Dv4.w, rx_prev.w, yv.w);
    *(float4*)&out[(size_t)prow * DI + d0 + lf] = o4;
  }
}

// ---------------------------------------------------------------------------
extern "C" void kernel_launch(void* const* d_in, const int* in_sizes, int n_in,
                              void* d_out, int out_size, void* d_ws, size_t ws_size,
                              hipStream_t stream) {
  const float* x     = (const float*)d_in[0];  // (2,512,4096)
  const float* A_log = (const float*)d_in[1];  // (4096,16)
  const float* Dv    = (const float*)d_in[2];  // (4096,)
  const float* W     = (const float*)d_in[3];  // (160,4096)
  const float* dtw   = (const float*)d_in[4];  // (4096,128)
  const float* dtb   = (const float*)d_in[5];  // (4096,)
  float* out = (float*)d_out;

  // Workspace: dtp [8][1024][128] bf16 (2 MB) + bcp [8][1024][32] f32 (1 MB)
  //          + dtin [1024][128] bf16 (256 KB) + BCf [1024][32] f32 (128 KB)
  char* ws = (char*)d_ws;
  bf16*  dtp  = (bf16*)ws;
  float* bcp  = (float*)(ws + (size_t)KSP * BL * RDT * sizeof(bf16));
  bf16*  dtin = (bf16*)(ws + (size_t)KSP * BL * RDT * sizeof(bf16)
                           + (size_t)KSP * BL * 32 * sizeof(float));
  float* BCf  = (float*)(ws + (size_t)KSP * BL * RDT * sizeof(bf16)
                            + (size_t)KSP * BL * 32 * sizeof(float)
                            + (size_t)BL * RDT * sizeof(bf16));

  gemm_part<<<dim3(64, KSP), 512, 0, stream>>>(x, W, dtp, bcp);
  reduce_slabs<<<dim3(160), 256, 0, stream>>>(dtp, bcp, dtin, BCf);
  scan_fused<<<dim3(512), 256, 0, stream>>>(x, A_log, Dv, BCf, dtin, dtw, dtb, out);
}